// Round 8
// baseline (253.356 us; speedup 1.0000x reference)
//
#include <hip/hip_runtime.h>

#define NB 512
#define NV 64
#define ND 32
#define NH 64
#define NE 4032

typedef short s16x8 __attribute__((ext_vector_type(8)));
typedef float f32x4 __attribute__((ext_vector_type(4)));
typedef unsigned int u32;

#define HLOG2PI 0.9189385332046727f
#define LOG2C   0.6931471805599453f

__device__ __forceinline__ unsigned short f2bf(float f){
  u32 u = __float_as_uint(f);
  u += 0x7FFFu + ((u >> 16) & 1u);
  return (unsigned short)(u >> 16);
}
__device__ __forceinline__ u32 pk2(float a, float b){
  return (u32)f2bf(a) | ((u32)f2bf(b) << 16);
}
// async global->LDS, 16B/lane; lds dst = wave-uniform base + lane*16
__device__ __forceinline__ void gload16(const void* g, void* l){
  __builtin_amdgcn_global_load_lds(
      (const __attribute__((address_space(1))) void*)g,
      (__attribute__((address_space(3))) void*)l, 16, 0, 0);
}

// ---------------- setup 1 (block-specialized) --------------------------------
// Wg (PLAIN col-major, global-read frags): W1_bot [64 j][32 k] | W2 [64 j][64 k]
// Fg (swizzled, LDS-staged by k_node): F1 [64][128] | F2 [64][64] | HW [16][64]

__global__ __launch_bounds__(256) void k_setup(
    const int* __restrict__ recv, const int* __restrict__ send,
    const float* __restrict__ x,
    const float* __restrict__ m1w, const float* __restrict__ m2w,
    const float* __restrict__ f1w, const float* __restrict__ f2w,
    const float* __restrict__ muw, const float* __restrict__ lsw,
    int* __restrict__ ebyv, int* __restrict__ sbyv,
    unsigned short* __restrict__ Wg, unsigned short* __restrict__ Fg,
    uint4* __restrict__ xbf)
{
  const int blk = blockIdx.x, t = threadIdx.x;
  if (blk == 0){
    __shared__ int cnt[NV];
    if (t < NV) cnt[t] = 0;
    __syncthreads();
    for (int e = t; e < NE; e += 256){
      int v = recv[e];
      int p = atomicAdd(&cnt[v], 1);
      ebyv[v*64 + p] = e;
      sbyv[v*64 + p] = send[e];
    }
    __syncthreads();
    if (t < NV){
      for (int s = cnt[t]; s < 64; s++){ ebyv[t*64 + s] = -1; sbyv[t*64 + s] = t; }
    }
  } else if (blk == 1){
    // W1 bottom half (send part, k=32..63), plain [j][32]
    #pragma unroll
    for (int i = 0; i < 8; i++){ int idx = i*256 + t; int kk = idx>>6, j = idx&63;
      Wg[j*32 + kk] = f2bf(m1w[(32+kk)*64 + j]); }
  } else if (blk == 2){
    // W2 plain [j][64]
    #pragma unroll
    for (int i = 0; i < 16; i++){ int idx = i*256 + t; int k = idx>>6, j = idx&63;
      Wg[2048 + j*64 + k] = f2bf(m2w[k*64 + j]); }
  } else if (blk == 3){
    #pragma unroll
    for (int i = 0; i < 24; i++){ int idx = i*256 + t; int k = idx>>6, j = idx&63;
      Fg[j*128 + (((k>>3)^(j&7))<<3) + (k&7)] = f2bf(f1w[idx]); }   // [96][64]
  } else if (blk == 4){
    #pragma unroll
    for (int i = 0; i < 16; i++){ int idx = i*256 + t; int k = idx>>6, j = idx&63;
      Fg[8192 + j*64 + (((k>>3)^(j&7))<<3) + (k&7)] = f2bf(f2w[idx]); }
  } else if (blk == 5){
    #pragma unroll
    for (int i = 0; i < 4; i++){ int idx = i*256 + t; int k = idx>>4, j = idx&15;
      float s = (j < 8) ? muw[k*8 + j] : lsw[k*8 + (j-8)];
      Fg[12288 + j*64 + (((k>>3)^(j&7))<<3) + (k&7)] = f2bf(s); }
  } else {
    int i = (blk - 6)*256 + t;
    const float4* s = (const float4*)x + i*2;
    float4 a = s[0], b = s[1];
    xbf[i] = make_uint4(pk2(a.x,a.y), pk2(a.z,a.w), pk2(b.x,b.y), pk2(b.z,b.w));
  }
}

// ---------------- setup 2: dense edge-weight gather (needs ebyv) -------------
// wgt[b][v][slot] f32; 100%-occupancy kernel hides the scattered edges reads.

__global__ __launch_bounds__(256) void k_gather(
    const float* __restrict__ edges, const int* __restrict__ ebyv,
    float* __restrict__ wgt)
{
  const int v = blockIdx.x & 63, b4 = blockIdx.x >> 6;
  const int slot = threadIdx.x & 63, w = threadIdx.x >> 6;
  const int b = b4*4 + w;
  int e = ebyv[v*64 + slot];
  float val = (e >= 0) ? edges[(b*NE + e)*2 + 1] : 0.0f;
  wgt[(b*64 + v)*64 + slot] = val;
}

// ---------------- kernel 1: edge MLP ----------------------------------------
// block = (v, 2 b's) x 2 row-halves; wave owns 32 edge-rows. Barrier-free main
// body: W frags from global (L1-hot), x frags from xbf (global), h handoff via
// 2KB/wave exchange, acc2 halved (32 f32) for occupancy. One end barrier to
// pair-sum the two row-half partials.

__global__ __launch_bounds__(256, 4) void k_msg(
    const unsigned short* __restrict__ xbf, const float* __restrict__ x,
    const float* __restrict__ wgt,
    const int* __restrict__ sbyv,
    const unsigned short* __restrict__ Wg, const float* __restrict__ m1w,
    const float* __restrict__ b1g, const float* __restrict__ b2g,
    float* __restrict__ out_aug)
{
  __shared__ __align__(16) char Hx[4][2048];   // per-wave h exchange (32r x 32j)
  __shared__ float b1eS[4][64];
  __shared__ float aggP[4][64];

  const int tid = threadIdx.x;
  const int w = tid >> 6, lane = tid & 63;
  const int l16 = lane & 15, l4 = lane >> 4;
  const int v = blockIdx.x & 63, bg2 = blockIdx.x >> 6;
  const int b = bg2*2 + (w >> 1);       // wave pair's batch row
  const int rh = w & 1;                 // row-half: rows rh*32 .. +32
  const int rowg = b*NV + v;

  // front loads: send indices -> x B-frags (rows rh*32 + il*16 + l16)
  int sv0 = sbyv[v*64 + rh*32 + l16];
  int sv1 = sbyv[v*64 + rh*32 + 16 + l16];
  s16x8 xf0 = *(const s16x8*)(xbf + (b*NV + sv0)*32 + l4*8);
  s16x8 xf1 = *(const s16x8*)(xbf + (b*NV + sv1)*32 + l4*8);

  // b1_eff[j] = b1[j] + x[b,v,:] @ W1_top[:,j]  (j = lane; L1-hot m1w)
  {
    float s = b1g[lane];
    const float* xr = x + rowg*ND;
    #pragma unroll 8
    for (int k = 0; k < 32; k++) s = fmaf(xr[k], m1w[k*64 + lane], s);
    b1eS[w][lane] = s;
  }

  const unsigned short* W1bg = Wg;          // [64 j][32 k]
  const unsigned short* W2g  = Wg + 2048;   // [64 j][64 k]
  char* Hw = Hx[w];

  f32x4 acc2[2][4] = {};                    // [im][jt], im = local row tile
  #pragma unroll
  for (int half = 0; half < 2; half++){
    // ---- layer 1: h[:, half*32..+32) = mfma(W1b cols, x rows) ----
    f32x4 a1[2][2] = {};                    // [jm][il]
    __builtin_amdgcn_s_setprio(1);
    #pragma unroll
    for (int jm = 0; jm < 2; jm++){
      s16x8 af = *(const s16x8*)(W1bg + (half*32 + jm*16 + l16)*32 + l4*8);
      a1[jm][0] = __builtin_amdgcn_mfma_f32_16x16x32_bf16(af, xf0, a1[jm][0], 0, 0, 0);
      a1[jm][1] = __builtin_amdgcn_mfma_f32_16x16x32_bf16(af, xf1, a1[jm][1], 0, 0, 0);
    }
    __builtin_amdgcn_s_setprio(0);
    // bias+relu+pack -> exchange (consumer frag layout)
    #pragma unroll
    for (int jm = 0; jm < 2; jm++){
      float4 bq = *(const float4*)&b1eS[w][half*32 + jm*16 + l4*4];
      #pragma unroll
      for (int il = 0; il < 2; il++){
        float h0 = fmaxf(a1[jm][il][0] + bq.x, 0.0f);
        float h1 = fmaxf(a1[jm][il][1] + bq.y, 0.0f);
        float h2 = fmaxf(a1[jm][il][2] + bq.z, 0.0f);
        float h3 = fmaxf(a1[jm][il][3] + bq.w, 0.0f);
        *(uint2*)(Hw + il*1024 + (jm*2 + (l4 >> 1))*256 + l16*16 + (l4 & 1)*8) =
            make_uint2(pk2(h0, h1), pk2(h2, h3));
      }
    }
    __builtin_amdgcn_sched_barrier(0);
    // ---- layer 2 partial-K: linear lane*16 reads (conflict-free) ----
    s16x8 hf0 = *(const s16x8*)(Hw + lane*16);
    s16x8 hf1 = *(const s16x8*)(Hw + 1024 + lane*16);
    __builtin_amdgcn_s_setprio(1);
    #pragma unroll
    for (int jt = 0; jt < 4; jt++){
      s16x8 wf = *(const s16x8*)(W2g + (jt*16 + l16)*64 + (half*4 + l4)*8);
      acc2[0][jt] = __builtin_amdgcn_mfma_f32_16x16x32_bf16(hf0, wf, acc2[0][jt], 0, 0, 0);
      acc2[1][jt] = __builtin_amdgcn_mfma_f32_16x16x32_bf16(hf1, wf, acc2[1][jt], 0, 0, 0);
    }
    __builtin_amdgcn_s_setprio(0);
    __builtin_amdgcn_sched_barrier(0);      // WAR: reads before next half's writes
  }

  // weighted i-reduce over this wave's 32 rows
  {
    float4 wq0 = *(const float4*)(wgt + rowg*64 + rh*32 + l4*4);
    float4 wq1 = *(const float4*)(wgt + rowg*64 + rh*32 + 16 + l4*4);
    #pragma unroll
    for (int jt = 0; jt < 4; jt++){
      float b2v = b2g[jt*16 + l16];
      float s = fmaxf(acc2[0][jt][0] + b2v, 0.0f) * wq0.x
              + fmaxf(acc2[0][jt][1] + b2v, 0.0f) * wq0.y
              + fmaxf(acc2[0][jt][2] + b2v, 0.0f) * wq0.z
              + fmaxf(acc2[0][jt][3] + b2v, 0.0f) * wq0.w
              + fmaxf(acc2[1][jt][0] + b2v, 0.0f) * wq1.x
              + fmaxf(acc2[1][jt][1] + b2v, 0.0f) * wq1.y
              + fmaxf(acc2[1][jt][2] + b2v, 0.0f) * wq1.z
              + fmaxf(acc2[1][jt][3] + b2v, 0.0f) * wq1.w;
      s += __shfl_xor(s, 16);
      s += __shfl_xor(s, 32);
      if (l4 == 0) aggP[w][jt*16 + l16] = s;
    }
  }
  __syncthreads();
  // pair-sum the two row-half partials, coalesced aug write
  if ((w & 1) == 0){
    float sum = aggP[w][lane] + aggP[w + 1][lane];
    out_aug[rowg*96 + 32 + lane] = sum;
    if (lane < 32) out_aug[rowg*96 + lane] = x[rowg*ND + lane];
  }
}

// ---------------- kernel 2: node MLP, wave-private 16 rows, 1 barrier --------

__global__ __launch_bounds__(256) void k_node(
    const float* __restrict__ aug,
    const unsigned short* __restrict__ Fg,
    const float* __restrict__ f1b, const float* __restrict__ f2b,
    const float* __restrict__ mub, const float* __restrict__ lsb,
    float* __restrict__ out0, float* __restrict__ out1)
{
  __shared__ __align__(16) unsigned short Wn[1664*8];  // F1 | F2 | HW (26KB)
  __shared__ __align__(16) char Hn[4][2048];           // per-wave exchange
  const unsigned short* F1 = Wn;
  const unsigned short* F2 = Wn + 8192;
  const unsigned short* HW = Wn + 12288;

  const int tid = threadIdx.x;
  const int w = tid >> 6, lane = tid & 63;
  const int l16 = lane & 15, l4 = lane >> 4;
  const int row = blockIdx.x*64 + w*16 + l16;   // this lane's B-column row

  #pragma unroll
  for (int i = 0; i < 7; i++){
    if (i*256 + w*64 < 1664)
      gload16(Fg + (i*256 + w*64 + lane)*8, (char*)Wn + i*4096 + w*1024);
  }
  // aug B-fragments (f32 -> bf16 in regs), K=96
  s16x8 bf1[3];
  #pragma unroll
  for (int ks = 0; ks < 3; ks++){
    const float4* p = (const float4*)(aug + row*96 + (ks*4 + l4)*8);
    float4 a = p[0], c = p[1];
    union { uint4 q; s16x8 v; } uu;
    uu.q = make_uint4(pk2(a.x,a.y), pk2(a.z,a.w), pk2(c.x,c.y), pk2(c.z,c.w));
    bf1[ks] = uu.v;
  }
  __syncthreads();

  const int sw8 = l16 & 7;
  char* Hw = Hn[w];

  // fc1: C[j][i] = mfma(F1 col j, aug row i)
  f32x4 a1[4] = {};
  #pragma unroll
  for (int ks = 0; ks < 3; ks++)
    #pragma unroll
    for (int jt = 0; jt < 4; jt++){
      s16x8 af = *(const s16x8*)(F1 + (jt*16 + l16)*128 + (((ks*4 + l4) ^ sw8) << 3));
      a1[jt] = __builtin_amdgcn_mfma_f32_16x16x32_bf16(af, bf1[ks], a1[jt], 0, 0, 0);
    }
  #pragma unroll
  for (int jt = 0; jt < 4; jt++){
    float4 bq = *(const float4*)(f1b + jt*16 + l4*4);
    float h0 = fmaxf(a1[jt][0] + bq.x, 0.0f);
    float h1 = fmaxf(a1[jt][1] + bq.y, 0.0f);
    float h2 = fmaxf(a1[jt][2] + bq.z, 0.0f);
    float h3 = fmaxf(a1[jt][3] + bq.w, 0.0f);
    *(uint2*)(Hw + (jt >> 1)*1024 + ((jt & 1)*2 + (l4 >> 1))*256 + l16*16 + (l4 & 1)*8) =
        make_uint2(pk2(h0, h1), pk2(h2, h3));
  }
  __builtin_amdgcn_sched_barrier(0);
  s16x8 bh[2];
  bh[0] = *(const s16x8*)(Hw + lane*16);
  bh[1] = *(const s16x8*)(Hw + 1024 + lane*16);
  // fc2
  f32x4 a2[4] = {};
  #pragma unroll
  for (int ks = 0; ks < 2; ks++)
    #pragma unroll
    for (int jt = 0; jt < 4; jt++){
      s16x8 af = *(const s16x8*)(F2 + (jt*16 + l16)*64 + (((ks*4 + l4) ^ sw8) << 3));
      a2[jt] = __builtin_amdgcn_mfma_f32_16x16x32_bf16(af, bh[ks], a2[jt], 0, 0, 0);
    }
  __builtin_amdgcn_sched_barrier(0);      // WAR before reusing Hw
  #pragma unroll
  for (int jt = 0; jt < 4; jt++){
    float4 bq = *(const float4*)(f2b + jt*16 + l4*4);
    float h0 = fmaxf(a2[jt][0] + bq.x, 0.0f);
    float h1 = fmaxf(a2[jt][1] + bq.y, 0.0f);
    float h2 = fmaxf(a2[jt][2] + bq.z, 0.0f);
    float h3 = fmaxf(a2[jt][3] + bq.w, 0.0f);
    *(uint2*)(Hw + (jt >> 1)*1024 + ((jt & 1)*2 + (l4 >> 1))*256 + l16*16 + (l4 & 1)*8) =
        make_uint2(pk2(h0, h1), pk2(h2, h3));
  }
  __builtin_amdgcn_sched_barrier(0);
  bh[0] = *(const s16x8*)(Hw + lane*16);
  bh[1] = *(const s16x8*)(Hw + 1024 + lane*16);
  // head: 16 cols (mu 0..7, ls 8..15)
  f32x4 a3 = {};
  #pragma unroll
  for (int ks = 0; ks < 2; ks++){
    s16x8 af = *(const s16x8*)(HW + l16*64 + (((ks*4 + l4) ^ sw8) << 3));
    a3 = __builtin_amdgcn_mfma_f32_16x16x32_bf16(af, bh[ks], a3, 0, 0, 0);
  }
  // epilogue: thread holds o = l4*4+r for its row
  float term = 0.0f;
  if (l4 < 2){
    float4 t;
    #pragma unroll
    for (int r = 0; r < 4; r++){
      int o = l4*4 + r;
      float mu = a3[r] + mub[o];
      ((float*)&t)[r] = tanhf(mu);
      float xm = -2.0f * mu;
      float sp = fmaxf(xm, 0.0f) + log1pf(expf(-fabsf(xm)));  // softplus(-2mu)
      term += -2.0f * (LOG2C - mu - sp);
    }
    *(float4*)(out0 + row*8 + l4*4) = t;
  } else {
    #pragma unroll
    for (int r = 0; r < 4; r++){
      float lsv = fminf(fmaxf(a3[r] + lsb[l4*4 + r - 8], -3.0f), 1.0f);
      term += -lsv - HLOG2PI;
    }
  }
  term += __shfl_xor(term, 16);
  term += __shfl_xor(term, 32);
  if (l4 == 0) out1[row] = term;
}

// ---------------- launch -----------------------------------------------------

extern "C" void kernel_launch(void* const* d_in, const int* in_sizes, int n_in,
                              void* d_out, int out_size, void* d_ws, size_t ws_size,
                              hipStream_t stream) {
  const float* x     = (const float*)d_in[0];
  const float* edges = (const float*)d_in[1];
  const float* m1w   = (const float*)d_in[2];
  const float* m1b   = (const float*)d_in[3];
  const float* m2w   = (const float*)d_in[4];
  const float* m2b   = (const float*)d_in[5];
  const float* f1w   = (const float*)d_in[6];
  const float* f1b   = (const float*)d_in[7];
  const float* f2w   = (const float*)d_in[8];
  const float* f2b   = (const float*)d_in[9];
  const float* muw   = (const float*)d_in[10];
  const float* mub   = (const float*)d_in[11];
  const float* lsw   = (const float*)d_in[12];
  const float* lsb   = (const float*)d_in[13];
  const int*   send  = (const int*)d_in[14];
  const int*   recv  = (const int*)d_in[15];

  char* ws = (char*)d_ws;
  int* ebyv = (int*)ws;                                   // 16 KB
  int* sbyv = (int*)(ws + 16384);                         // 16 KB
  unsigned short* Wg  = (unsigned short*)(ws + 32768);    // 12 KB: W1b | W2 (plain)
  unsigned short* Fg  = (unsigned short*)(ws + 49152);    // 26 KB: F1 | F2 | HW
  unsigned short* xbf = (unsigned short*)(ws + 75776);    // 2 MB bf16 x
  float* wgt          = (float*)(ws + 2172928);           // 8 MB dense edge w

  float* out0    = (float*)d_out;        // tanh(mu) [B,V,8]
  float* out1    = out0 + NB*NV*8;       // logp [B,V]
  float* out_aug = out1 + NB*NV;         // aug [B,V,96]

  k_setup<<<6 + NB*NV*ND/2048, 256, 0, stream>>>(recv, send, x, m1w, m2w,
                                                 f1w, f2w, muw, lsw,
                                                 ebyv, sbyv, Wg, Fg, (uint4*)xbf);
  k_gather<<<(NB/4)*NV, 256, 0, stream>>>(edges, ebyv, wgt);
  k_msg<<<(NB/2)*NV, 256, 0, stream>>>(xbf, x, wgt, sbyv, Wg, m1w,
                                       m1b, m2b, out_aug);
  k_node<<<NB*NV/64, 256, 0, stream>>>(out_aug, Fg, f1b, f2b, mub, lsb, out0, out1);
}

// Round 9
// 152.724 us; speedup vs baseline: 1.6589x; 1.6589x over previous
//
#include <hip/hip_runtime.h>

#define NB 512
#define NV 64
#define ND 32
#define NH 64
#define NE 4032

typedef short s16x8 __attribute__((ext_vector_type(8)));
typedef float f32x4 __attribute__((ext_vector_type(4)));
typedef unsigned int u32;

#define HLOG2PI 0.9189385332046727f
#define LOG2C   0.6931471805599453f

__device__ __forceinline__ unsigned short f2bf(float f){
  u32 u = __float_as_uint(f);
  u += 0x7FFFu + ((u >> 16) & 1u);
  return (unsigned short)(u >> 16);
}
__device__ __forceinline__ u32 pk2(float a, float b){
  return (u32)f2bf(a) | ((u32)f2bf(b) << 16);
}
// async global->LDS, 16B/lane; lds dst = wave-uniform base + lane*16
__device__ __forceinline__ void gload16(const void* g, void* l){
  __builtin_amdgcn_global_load_lds(
      (const __attribute__((address_space(1))) void*)g,
      (__attribute__((address_space(3))) void*)l, 16, 0, 0);
}

// ---------------- setup (1 launch, block-specialized) ------------------------
// Wg: [0,2048) W1b plain [64 j][32 k] | [2048,4096) W1t plain | [4096,8192) W2 swz
// Fg: F1 [64][128] | F2 [64][64] | HW [16][64]  (all swizzled, staged by k_node)

__global__ __launch_bounds__(256) void k_setup(
    const float* __restrict__ x,
    const float* __restrict__ m1w, const float* __restrict__ m2w,
    const float* __restrict__ f1w, const float* __restrict__ f2w,
    const float* __restrict__ muw, const float* __restrict__ lsw,
    unsigned short* __restrict__ Wg, unsigned short* __restrict__ Fg,
    uint4* __restrict__ xbf)
{
  const int blk = blockIdx.x, t = threadIdx.x;
  if (blk == 0){
    // W1 bottom (send part, rows 32..63 of m1w), plain col image [j][32]
    #pragma unroll
    for (int i = 0; i < 8; i++){ int idx = i*256 + t; int kk = idx>>6, j = idx&63;
      Wg[j*32 + kk] = f2bf(m1w[(32+kk)*64 + j]); }
  } else if (blk == 1){
    // W1 top (recv part, rows 0..31), plain col image
    #pragma unroll
    for (int i = 0; i < 8; i++){ int idx = i*256 + t; int kk = idx>>6, j = idx&63;
      Wg[2048 + j*32 + kk] = f2bf(m1w[kk*64 + j]); }
  } else if (blk == 2){
    // W2 swizzled col image [j][64]
    #pragma unroll
    for (int i = 0; i < 16; i++){ int idx = i*256 + t; int k = idx>>6, j = idx&63;
      Wg[4096 + j*64 + (((k>>3)^(j&7))<<3) + (k&7)] = f2bf(m2w[idx]); }
  } else if (blk == 3){
    #pragma unroll
    for (int i = 0; i < 24; i++){ int idx = i*256 + t; int k = idx>>6, j = idx&63;
      Fg[j*128 + (((k>>3)^(j&7))<<3) + (k&7)] = f2bf(f1w[idx]); }   // [96][64]
  } else if (blk == 4){
    #pragma unroll
    for (int i = 0; i < 16; i++){ int idx = i*256 + t; int k = idx>>6, j = idx&63;
      Fg[8192 + j*64 + (((k>>3)^(j&7))<<3) + (k&7)] = f2bf(f2w[idx]); }
  } else if (blk == 5){
    #pragma unroll
    for (int i = 0; i < 4; i++){ int idx = i*256 + t; int k = idx>>4, j = idx&15;
      float s = (j < 8) ? muw[k*8 + j] : lsw[k*8 + (j-8)];
      Fg[12288 + j*64 + (((k>>3)^(j&7))<<3) + (k&7)] = f2bf(s); }
  } else {
    int i = (blk - 6)*256 + t;
    const float4* s = (const float4*)x + i*2;
    float4 a = s[0], b = s[1];
    xbf[i] = make_uint4(pk2(a.x,a.y), pk2(a.z,a.w), pk2(b.x,b.y), pk2(b.z,b.w));
  }
}

// ---------------- kernel 1: edge MLP via per-node factorization --------------
// block = (b, 8 v's). Per b: C[v]=x[v]@W1t+b1, G[s]=x[s]@W1b (8 MFMA/wave) into
// LDS (G 16B-XOR swizzled). Then wave owns 2 v's: h-frag = relu(C+G) built in
// registers, layer-2 jt-sequential (16-reg acc), weighted reduce, aug write.
// Graph is closed-form: sender(slot,v) = slot + (slot>=v); e = s*63+v-(v>s).

__global__ __launch_bounds__(256, 4) void k_msg(
    const unsigned short* __restrict__ xbf, const float* __restrict__ x,
    const float* __restrict__ edges,
    const unsigned short* __restrict__ Wg,
    const float* __restrict__ b1g, const float* __restrict__ b2g,
    float* __restrict__ out_aug)
{
  __shared__ __align__(16) float Gt[64*64];            // 16KB, 16B-XOR swz
  __shared__ __align__(16) float Ct[16*64];            // 4KB plain (rows 0..7 used)
  __shared__ __align__(16) unsigned short W2l[4096];   // 8KB swz image
  __shared__ __align__(16) float wgtl[8][64];          // 2KB

  const int tid = threadIdx.x;
  const int w = tid >> 6, lane = tid & 63;
  const int l16 = lane & 15, l4 = lane >> 4;
  const int b = blockIdx.x >> 3, v0 = (blockIdx.x & 7) << 3;

  // stage W2 image (linear 16B chunks)
  gload16(Wg + 4096 + tid*8,        (char*)W2l + w*1024);
  gload16(Wg + 4096 + (256+tid)*8,  (char*)W2l + 4096 + w*1024);

  // stage edge weights for the 8 v's (closed-form e)
  #pragma unroll
  for (int it = 0; it < 2; it++){
    int idx = it*256 + tid;
    int vi = idx >> 6, slot = idx & 63;
    int v = v0 + vi;
    float val = 0.0f;
    if (slot < 63){
      int s = slot + (slot >= v ? 1 : 0);
      int e = s*63 + v - (v > s ? 1 : 0);
      val = edges[(b*NE + e)*2 + 1];
    }
    wgtl[vi][slot] = val;
  }

  // G-gemm: rows s = w*16..+16 ; C-gemm on wave 0 (rows v0..v0+7 duplicated)
  {
    s16x8 xg = *(const s16x8*)(xbf + (b*NV + w*16 + l16)*32 + l4*8);
    f32x4 accG[4];
    #pragma unroll
    for (int jt = 0; jt < 4; jt++){
      s16x8 wb = *(const s16x8*)(Wg + (jt*16 + l16)*32 + l4*8);
      f32x4 z = {0.0f, 0.0f, 0.0f, 0.0f};
      accG[jt] = __builtin_amdgcn_mfma_f32_16x16x32_bf16(xg, wb, z, 0, 0, 0);
    }
    #pragma unroll
    for (int jt = 0; jt < 4; jt++){
      int j = jt*16 + l16;
      #pragma unroll
      for (int r = 0; r < 4; r++){
        int s = w*16 + l4*4 + r;
        *(float*)((char*)Gt + s*256 + (((j >> 2) ^ (s & 7)) << 4) + (j & 3)*4)
            = accG[jt][r];
      }
    }
    if (w == 0){
      s16x8 xc = *(const s16x8*)(xbf + (b*NV + v0 + (l16 & 7))*32 + l4*8);
      #pragma unroll
      for (int jt = 0; jt < 4; jt++){
        s16x8 wt = *(const s16x8*)(Wg + 2048 + (jt*16 + l16)*32 + l4*8);
        float b1v = b1g[jt*16 + l16];
        f32x4 ci = {b1v, b1v, b1v, b1v};
        f32x4 cc = __builtin_amdgcn_mfma_f32_16x16x32_bf16(xc, wt, ci, 0, 0, 0);
        #pragma unroll
        for (int r = 0; r < 4; r++)
          Ct[(l4*4 + r)*64 + jt*16 + l16] = cc[r];
      }
    }
  }
  __syncthreads();

  // ---- per-wave v loop (2 v's), barrier-free ----
  #pragma unroll
  for (int vi = 0; vi < 2; vi++){
    const int vloc = w*2 + vi, v = v0 + vloc;
    // build h A-frags: rows slot = im*16 + l16, k-octets (ks,l4)
    s16x8 hf[4][2];
    #pragma unroll
    for (int im = 0; im < 4; im++){
      int slot = im*16 + l16;
      int s = slot + (slot >= v ? 1 : 0);
      s = s > 63 ? 63 : s;                       // pad slot 63
      int sx = s & 7;
      const char* Gr = (char*)Gt + s*256;
      #pragma unroll
      for (int ks = 0; ks < 2; ks++){
        int c0 = ks*8 + l4*2;
        float4 ga = *(const float4*)(Gr + ((c0 ^ sx) << 4));
        float4 gb = *(const float4*)(Gr + (((c0 + 1) ^ sx) << 4));
        const float* Cp = Ct + vloc*64 + ks*32 + l4*8;
        float4 ca = *(const float4*)(Cp);
        float4 cb = *(const float4*)(Cp + 4);
        union { uint4 q; s16x8 h; } uu;
        uu.q.x = pk2(fmaxf(ga.x + ca.x, 0.0f), fmaxf(ga.y + ca.y, 0.0f));
        uu.q.y = pk2(fmaxf(ga.z + ca.z, 0.0f), fmaxf(ga.w + ca.w, 0.0f));
        uu.q.z = pk2(fmaxf(gb.x + cb.x, 0.0f), fmaxf(gb.y + cb.y, 0.0f));
        uu.q.w = pk2(fmaxf(gb.z + cb.z, 0.0f), fmaxf(gb.w + cb.w, 0.0f));
        hf[im][ks] = uu.h;
      }
    }
    // layer-2: jt-sequential, 16-reg acc; immediate weighted reduce
    float aggj[4];
    #pragma unroll
    for (int jt = 0; jt < 4; jt++){
      int cb = (jt*16 + l16)*64;
      int sw = (l16 & 7) << 3;
      s16x8 wf0 = *(const s16x8*)(W2l + cb + ((l4 << 3) ^ sw));
      s16x8 wf1 = *(const s16x8*)(W2l + cb + (((4 + l4) << 3) ^ sw));
      float b2v = b2g[jt*16 + l16];
      float ssum = 0.0f;
      #pragma unroll
      for (int im = 0; im < 4; im++){
        f32x4 a = {0.0f, 0.0f, 0.0f, 0.0f};
        a = __builtin_amdgcn_mfma_f32_16x16x32_bf16(hf[im][0], wf0, a, 0, 0, 0);
        a = __builtin_amdgcn_mfma_f32_16x16x32_bf16(hf[im][1], wf1, a, 0, 0, 0);
        float4 wq = *(const float4*)&wgtl[vloc][im*16 + l4*4];
        ssum += fmaxf(a[0] + b2v, 0.0f) * wq.x;
        ssum += fmaxf(a[1] + b2v, 0.0f) * wq.y;
        ssum += fmaxf(a[2] + b2v, 0.0f) * wq.z;
        ssum += fmaxf(a[3] + b2v, 0.0f) * wq.w;
      }
      ssum += __shfl_xor(ssum, 16);
      ssum += __shfl_xor(ssum, 32);
      aggj[jt] = ssum;
    }
    const int rowg = b*NV + v;
    if (l4 == 0){
      #pragma unroll
      for (int jt = 0; jt < 4; jt++)
        out_aug[rowg*96 + 32 + jt*16 + l16] = aggj[jt];
    } else if (lane >= 16 && lane < 48){
      out_aug[rowg*96 + (lane - 16)] = x[rowg*ND + (lane - 16)];
    }
  }
}

// ---------------- kernel 2: node MLP, wave-private 16 rows (proven) ----------

__global__ __launch_bounds__(256) void k_node(
    const float* __restrict__ aug,
    const unsigned short* __restrict__ Fg,
    const float* __restrict__ f1b, const float* __restrict__ f2b,
    const float* __restrict__ mub, const float* __restrict__ lsb,
    float* __restrict__ out0, float* __restrict__ out1)
{
  __shared__ __align__(16) unsigned short Wn[1664*8];  // F1 | F2 | HW (26KB)
  __shared__ __align__(16) char Hn[4][2048];           // per-wave exchange
  const unsigned short* F1 = Wn;
  const unsigned short* F2 = Wn + 8192;
  const unsigned short* HW = Wn + 12288;

  const int tid = threadIdx.x;
  const int w = tid >> 6, lane = tid & 63;
  const int l16 = lane & 15, l4 = lane >> 4;
  const int row = blockIdx.x*64 + w*16 + l16;

  #pragma unroll
  for (int i = 0; i < 7; i++){
    if (i*256 + w*64 < 1664)
      gload16(Fg + (i*256 + w*64 + lane)*8, (char*)Wn + i*4096 + w*1024);
  }
  s16x8 bf1[3];
  #pragma unroll
  for (int ks = 0; ks < 3; ks++){
    const float4* p = (const float4*)(aug + row*96 + (ks*4 + l4)*8);
    float4 a = p[0], c = p[1];
    union { uint4 q; s16x8 v; } uu;
    uu.q = make_uint4(pk2(a.x,a.y), pk2(a.z,a.w), pk2(c.x,c.y), pk2(c.z,c.w));
    bf1[ks] = uu.v;
  }
  __syncthreads();

  const int sw8 = l16 & 7;
  char* Hw = Hn[w];

  f32x4 a1[4] = {};
  #pragma unroll
  for (int ks = 0; ks < 3; ks++)
    #pragma unroll
    for (int jt = 0; jt < 4; jt++){
      s16x8 af = *(const s16x8*)(F1 + (jt*16 + l16)*128 + (((ks*4 + l4) ^ sw8) << 3));
      a1[jt] = __builtin_amdgcn_mfma_f32_16x16x32_bf16(af, bf1[ks], a1[jt], 0, 0, 0);
    }
  #pragma unroll
  for (int jt = 0; jt < 4; jt++){
    float4 bq = *(const float4*)(f1b + jt*16 + l4*4);
    float h0 = fmaxf(a1[jt][0] + bq.x, 0.0f);
    float h1 = fmaxf(a1[jt][1] + bq.y, 0.0f);
    float h2 = fmaxf(a1[jt][2] + bq.z, 0.0f);
    float h3 = fmaxf(a1[jt][3] + bq.w, 0.0f);
    *(uint2*)(Hw + (jt >> 1)*1024 + ((jt & 1)*2 + (l4 >> 1))*256 + l16*16 + (l4 & 1)*8) =
        make_uint2(pk2(h0, h1), pk2(h2, h3));
  }
  __builtin_amdgcn_sched_barrier(0);
  s16x8 bh[2];
  bh[0] = *(const s16x8*)(Hw + lane*16);
  bh[1] = *(const s16x8*)(Hw + 1024 + lane*16);
  f32x4 a2[4] = {};
  #pragma unroll
  for (int ks = 0; ks < 2; ks++)
    #pragma unroll
    for (int jt = 0; jt < 4; jt++){
      s16x8 af = *(const s16x8*)(F2 + (jt*16 + l16)*64 + (((ks*4 + l4) ^ sw8) << 3));
      a2[jt] = __builtin_amdgcn_mfma_f32_16x16x32_bf16(af, bh[ks], a2[jt], 0, 0, 0);
    }
  __builtin_amdgcn_sched_barrier(0);
  #pragma unroll
  for (int jt = 0; jt < 4; jt++){
    float4 bq = *(const float4*)(f2b + jt*16 + l4*4);
    float h0 = fmaxf(a2[jt][0] + bq.x, 0.0f);
    float h1 = fmaxf(a2[jt][1] + bq.y, 0.0f);
    float h2 = fmaxf(a2[jt][2] + bq.z, 0.0f);
    float h3 = fmaxf(a2[jt][3] + bq.w, 0.0f);
    *(uint2*)(Hw + (jt >> 1)*1024 + ((jt & 1)*2 + (l4 >> 1))*256 + l16*16 + (l4 & 1)*8) =
        make_uint2(pk2(h0, h1), pk2(h2, h3));
  }
  __builtin_amdgcn_sched_barrier(0);
  bh[0] = *(const s16x8*)(Hw + lane*16);
  bh[1] = *(const s16x8*)(Hw + 1024 + lane*16);
  f32x4 a3 = {};
  #pragma unroll
  for (int ks = 0; ks < 2; ks++){
    s16x8 af = *(const s16x8*)(HW + l16*64 + (((ks*4 + l4) ^ sw8) << 3));
    a3 = __builtin_amdgcn_mfma_f32_16x16x32_bf16(af, bh[ks], a3, 0, 0, 0);
  }
  float term = 0.0f;
  if (l4 < 2){
    float4 t;
    #pragma unroll
    for (int r = 0; r < 4; r++){
      int o = l4*4 + r;
      float mu = a3[r] + mub[o];
      ((float*)&t)[r] = tanhf(mu);
      float xm = -2.0f * mu;
      float sp = fmaxf(xm, 0.0f) + log1pf(expf(-fabsf(xm)));  // softplus(-2mu)
      term += -2.0f * (LOG2C - mu - sp);
    }
    *(float4*)(out0 + row*8 + l4*4) = t;
  } else {
    #pragma unroll
    for (int r = 0; r < 4; r++){
      float lsv = fminf(fmaxf(a3[r] + lsb[l4*4 + r - 8], -3.0f), 1.0f);
      term += -lsv - HLOG2PI;
    }
  }
  term += __shfl_xor(term, 16);
  term += __shfl_xor(term, 32);
  if (l4 == 0) out1[row] = term;
}

// ---------------- launch -----------------------------------------------------

extern "C" void kernel_launch(void* const* d_in, const int* in_sizes, int n_in,
                              void* d_out, int out_size, void* d_ws, size_t ws_size,
                              hipStream_t stream) {
  const float* x     = (const float*)d_in[0];
  const float* edges = (const float*)d_in[1];
  const float* m1w   = (const float*)d_in[2];
  const float* m1b   = (const float*)d_in[3];
  const float* m2w   = (const float*)d_in[4];
  const float* m2b   = (const float*)d_in[5];
  const float* f1w   = (const float*)d_in[6];
  const float* f1b   = (const float*)d_in[7];
  const float* f2w   = (const float*)d_in[8];
  const float* f2b   = (const float*)d_in[9];
  const float* muw   = (const float*)d_in[10];
  const float* mub   = (const float*)d_in[11];
  const float* lsw   = (const float*)d_in[12];
  const float* lsb   = (const float*)d_in[13];

  char* ws = (char*)d_ws;
  unsigned short* Wg  = (unsigned short*)ws;              // 16 KB: W1b|W1t|W2
  unsigned short* Fg  = (unsigned short*)(ws + 16384);    // 26 KB: F1|F2|HW
  unsigned short* xbf = (unsigned short*)(ws + 49152);    // 2 MB bf16 x

  float* out0    = (float*)d_out;        // tanh(mu) [B,V,8]
  float* out1    = out0 + NB*NV*8;       // logp [B,V]
  float* out_aug = out1 + NB*NV;         // aug [B,V,96]

  k_setup<<<6 + NB*NV*ND/2048, 256, 0, stream>>>(x, m1w, m2w, f1w, f2w, muw, lsw,
                                                 Wg, Fg, (uint4*)xbf);
  k_msg<<<NB*8, 256, 0, stream>>>(xbf, x, edges, Wg, m1b, m2b, out_aug);
  k_node<<<NB*NV/64, 256, 0, stream>>>(out_aug, Fg, f1b, f2b, mub, lsb, out0, out1);
}